// Round 6
// baseline (290.894 us; speedup 1.0000x reference)
//
#include <hip/hip_runtime.h>
#include <cstdint>

// Problem constants (x: [64, 768, 28, 28] fp32)
#define B_   64
#define C_   768
#define HID_ 192
#define HW_  784                 // 28*28
#define NCHAN (B_ * C_)          // 49152
#define V4PC (HW_ / 4)           // 196 float4 per channel

typedef float vfloat4 __attribute__((ext_vector_type(4)));

// ---------- Kernel 1: global avg pool, persistent waves, 3 channels/wave --------
// Round-5 pool (one-shot wave per channel, 12288 blocks) measured ~58 us
// (2.6 TB/s) by ledger arithmetic: each wave issues 4 loads, eats a full
// ~900 cy cold-HBM round trip, reduces, exits -- MLP throttled by the
// launch/drain cycle. This version: 4096 blocks, each wave owns 3 contiguous
// channels and issues ALL 12 vec4 loads (static-indexed register arrays)
// before any reduction. ~60 VGPR keeps 8 waves/SIMD; 32 waves/CU x 12 KB
// in flight >> the ~9 KB/CU needed to saturate HBM.
__global__ __launch_bounds__(256) void pool_kernel(const float* __restrict__ x,
                                                   float* __restrict__ pooledT) {
    const int gw   = (int)((blockIdx.x * 256 + threadIdx.x) >> 6);  // wave 0..16383
    const int lane = threadIdx.x & 63;
    const int ch0  = gw * 3;

    const vfloat4* p0 = (const vfloat4*)(x + (size_t)(ch0 + 0) * HW_);
    const vfloat4* p1 = (const vfloat4*)(x + (size_t)(ch0 + 1) * HW_);
    const vfloat4* p2 = (const vfloat4*)(x + (size_t)(ch0 + 2) * HW_);

    // issue all main loads first (12 independent dwordx4 -> deep MLP)
    vfloat4 a0 = p0[lane], a1 = p0[lane + 64], a2 = p0[lane + 128];
    vfloat4 b0 = p1[lane], b1 = p1[lane + 64], b2 = p1[lane + 128];
    vfloat4 c0 = p2[lane], c1 = p2[lane + 64], c2 = p2[lane + 128];
    // tail float4 indices 192..195 (4 lanes per channel)
    vfloat4 a3 = {0,0,0,0}, b3 = {0,0,0,0}, c3 = {0,0,0,0};
    if (lane < V4PC - 192) { a3 = p0[lane + 192]; b3 = p1[lane + 192]; c3 = p2[lane + 192]; }

    float s0 = (a0.x + a0.y + a0.z + a0.w) + (a1.x + a1.y + a1.z + a1.w)
             + (a2.x + a2.y + a2.z + a2.w) + (a3.x + a3.y + a3.z + a3.w);
    float s1 = (b0.x + b0.y + b0.z + b0.w) + (b1.x + b1.y + b1.z + b1.w)
             + (b2.x + b2.y + b2.z + b2.w) + (b3.x + b3.y + b3.z + b3.w);
    float s2 = (c0.x + c0.y + c0.z + c0.w) + (c1.x + c1.y + c1.z + c1.w)
             + (c2.x + c2.y + c2.z + c2.w) + (c3.x + c3.y + c3.z + c3.w);

    #pragma unroll
    for (int off = 32; off > 0; off >>= 1) {
        s0 += __shfl_down(s0, off, 64);
        s1 += __shfl_down(s1, off, 64);
        s2 += __shfl_down(s2, off, 64);
    }
    if (lane == 0) {
        #pragma unroll
        for (int i = 0; i < 3; ++i) {
            const int ch = ch0 + i;
            const float s = (i == 0) ? s0 : (i == 1) ? s1 : s2;
            pooledT[(ch % C_) * B_ + (ch / C_)] = s * (1.0f / (float)HW_);
        }
    }
}

// ---------- Kernel 2: FC1 + ReLU, weight-stationary over batch ----------
// 192 blocks: block k owns hidden unit k. w1 row k (3 KB) staged in LDS once;
// thread (q = t>>6, b = t&63) dots quarter q of column b. Weights cross the
// fabric ONCE total (round 2's 77 MB FETCH was 64 re-reads of w1+w2 at
// single-block occupancy -- never batch-per-block for the FC stack).
__global__ __launch_bounds__(256) void fc1_kernel(const float* __restrict__ pooledT,
                                                  const float* __restrict__ w1,
                                                  const float* __restrict__ b1,
                                                  float* __restrict__ hT) {
    __shared__ float w[C_];
    __shared__ float part[4][B_];
    const int k = blockIdx.x;
    const int t = threadIdx.x;
    if (t < C_ / 4) ((vfloat4*)w)[t] = ((const vfloat4*)(w1 + (size_t)k * C_))[t];
    __syncthreads();

    const int q = t >> 6, b = t & 63;
    const float* pc = pooledT + q * 192 * B_ + b;   // column b, rows q*192..+191
    const float* wq = w + q * 192;                  // wave-uniform LDS broadcast
    float a0 = 0.f, a1 = 0.f, a2 = 0.f, a3 = 0.f;
    #pragma unroll 4
    for (int j = 0; j < 192; j += 4) {              // coalesced 256 B wave loads
        a0 += pc[(j + 0) * B_] * wq[j + 0];
        a1 += pc[(j + 1) * B_] * wq[j + 1];
        a2 += pc[(j + 2) * B_] * wq[j + 2];
        a3 += pc[(j + 3) * B_] * wq[j + 3];
    }
    part[q][b] = (a0 + a1) + (a2 + a3);
    __syncthreads();
    if (t < B_) {
        float h = part[0][t] + part[1][t] + part[2][t] + part[3][t] + b1[k];
        hT[k * B_ + t] = h > 0.f ? h : 0.f;         // transposed: coalesced store
    }
}

// ---------- Kernel 3: FC2 + hardsigmoid + scale, fused, batch-split for TLP ----
// Grid 768 x 4: block (c, g) gates and streams batches 16g..16g+15 of channel c.
// Prologue: thread (p = t>>4, bl = t&15) dots K-segment p (12 floats) of hT
// column (16g+bl) against w2 row c (LDS); 16-way LDS reduce -> 16 gates.
__global__ __launch_bounds__(256) void fc2scale_kernel(const float* __restrict__ hT,
                                                       const float* __restrict__ w2,
                                                       const float* __restrict__ b2,
                                                       const float* __restrict__ x,
                                                       float* __restrict__ out) {
    __shared__ float w[HID_];
    __shared__ float part[16][16];
    __shared__ float gate[16];
    const int c = blockIdx.x >> 2;
    const int g = blockIdx.x & 3;
    const int t = threadIdx.x;
    if (t < HID_ / 4)
        ((vfloat4*)w)[t] = ((const vfloat4*)(w2 + (size_t)c * HID_))[t];
    __syncthreads();

    {   // FC2 dot: K-segment p (12 floats) of column (16g + bl)
        const int p = t >> 4, bl = t & 15;
        const float* hc = hT + p * 12 * B_ + g * 16 + bl;
        const float* wp = w + p * 12;
        float a0 = 0.f, a1 = 0.f, a2 = 0.f;
        #pragma unroll
        for (int j = 0; j < 12; j += 3) {
            a0 += hc[(j + 0) * B_] * wp[j + 0];
            a1 += hc[(j + 1) * B_] * wp[j + 1];
            a2 += hc[(j + 2) * B_] * wp[j + 2];
        }
        part[p][bl] = (a0 + a1) + a2;
    }
    __syncthreads();
    if (t < 16) {
        float z = b2[c];
        #pragma unroll
        for (int p = 0; p < 16; ++p) z += part[p][t];
        float sg = z * (1.0f / 6.0f) + 0.5f;
        gate[t] = sg < 0.f ? 0.f : (sg > 1.f ? 1.f : sg);
    }
    __syncthreads();

    // scale phase: 4 waves x 4 batch-images each
    const int wv = t >> 6, lane = t & 63;
    #pragma unroll
    for (int i = 0; i < 4; ++i) {
        const int bl = wv * 4 + i;                  // local batch 0..15
        const float sc = gate[bl];                  // uniform LDS broadcast
        const size_t chan = (size_t)(g * 16 + bl) * C_ + c;
        const vfloat4* p = (const vfloat4*)(x + chan * HW_);
        vfloat4* qo = (vfloat4*)(out + chan * HW_);
        vfloat4 v0 = p[lane];
        vfloat4 v1 = p[lane + 64];
        vfloat4 v2 = p[lane + 128];
        __builtin_nontemporal_store(v0 * sc, qo + lane);
        __builtin_nontemporal_store(v1 * sc, qo + lane + 64);
        __builtin_nontemporal_store(v2 * sc, qo + lane + 128);
        if (lane < V4PC - 192) {                    // tail float4 192..195
            vfloat4 v3 = p[lane + 192];
            __builtin_nontemporal_store(v3 * sc, qo + lane + 192);
        }
    }
}

extern "C" void kernel_launch(void* const* d_in, const int* in_sizes, int n_in,
                              void* d_out, int out_size, void* d_ws, size_t ws_size,
                              hipStream_t stream) {
    const float* x  = (const float*)d_in[0];
    const float* w1 = (const float*)d_in[1];
    const float* b1 = (const float*)d_in[2];
    const float* w2 = (const float*)d_in[3];
    const float* b2 = (const float*)d_in[4];
    float* out = (float*)d_out;

    float* pooledT = (float*)d_ws;                       // C*B fp32 = 192 KiB
    float* hT      = pooledT + C_ * B_;                  // HID*B fp32 = 48 KiB

    pool_kernel    <<<NCHAN / 12, 256, 0, stream>>>(x, pooledT);  // 4096 blocks
    fc1_kernel     <<<HID_,       256, 0, stream>>>(pooledT, w1, b1, hT);
    fc2scale_kernel<<<C_ * 4,     256, 0, stream>>>(hT, w2, b2, x, out);
}